// Round 8
// baseline (684.477 us; speedup 1.0000x reference)
//
#include <hip/hip_runtime.h>

// Problem constants (match reference)
#define NB 32768   // batch rows
#define NF 256     // features
#define NH 8       // hidden dim
#define ROWS_PER_BLOCK 32

// One thread per feature; 96 MLP params in registers (launch_bounds(256,3)
// caps VGPR at ~168 so they stay resident). KEY CHANGE vs rounds 2-7: the row
// loop is ROLLED (#pragma unroll 2, ~1.6 KB body) instead of fully unrolled
// (~28 KB straight-line code that thrashed L1I and capped issue at ~40%).
// x-loads use a depth-2 register prefetch pipeline (branchless clamped tail).
// Results go to LDS; one barrier; store+reduce phase emits coalesced dwordx4
// out_w stores and the per-row sum butterfly, all fire-and-forget.
__global__ __launch_bounds__(256, 3) void NAM_49314814493074_kernel(
    const float* __restrict__ input,   // [B, F]
    const float* __restrict__ W1,      // [F, 8]
    const float* __restrict__ b1,      // [F, 8]
    const float* __restrict__ W2,      // [F, 8, 8]
    const float* __restrict__ b2,      // [F, 8]
    const float* __restrict__ W3,      // [F, 8]
    float* __restrict__ out_sum,       // [B]
    float* __restrict__ out_w)         // [B, F]
{
    __shared__ float sred[ROWS_PER_BLOCK][NF];   // 32 KB

    const int f = threadIdx.x;                  // feature index 0..255
    const int row0 = blockIdx.x * ROWS_PER_BLOCK;

    // ---- params first: the only loads whose latency is ever exposed ----
    float w1[NH], bb1[NH], bb2[NH], w3[NH];
    float w2[NH][NH];
    {
        const float4* p1  = reinterpret_cast<const float4*>(W1 + (size_t)f * NH);
        const float4* pb1 = reinterpret_cast<const float4*>(b1 + (size_t)f * NH);
        const float4* pb2 = reinterpret_cast<const float4*>(b2 + (size_t)f * NH);
        const float4* p3  = reinterpret_cast<const float4*>(W3 + (size_t)f * NH);
        float4 a, b;
        a = p1[0]; b = p1[1];
        w1[0]=a.x; w1[1]=a.y; w1[2]=a.z; w1[3]=a.w; w1[4]=b.x; w1[5]=b.y; w1[6]=b.z; w1[7]=b.w;
        a = pb1[0]; b = pb1[1];
        bb1[0]=a.x; bb1[1]=a.y; bb1[2]=a.z; bb1[3]=a.w; bb1[4]=b.x; bb1[5]=b.y; bb1[6]=b.z; bb1[7]=b.w;
        a = pb2[0]; b = pb2[1];
        bb2[0]=a.x; bb2[1]=a.y; bb2[2]=a.z; bb2[3]=a.w; bb2[4]=b.x; bb2[5]=b.y; bb2[6]=b.z; bb2[7]=b.w;
        a = p3[0]; b = p3[1];
        w3[0]=a.x; w3[1]=a.y; w3[2]=a.z; w3[3]=a.w; w3[4]=b.x; w3[5]=b.y; w3[6]=b.z; w3[7]=b.w;

        const float4* p2 = reinterpret_cast<const float4*>(W2 + (size_t)f * NH * NH);
        #pragma unroll
        for (int h = 0; h < NH; ++h) {
            float4 c0 = p2[h * 2 + 0];
            float4 c1 = p2[h * 2 + 1];
            w2[h][0]=c0.x; w2[h][1]=c0.y; w2[h][2]=c0.z; w2[h][3]=c0.w;
            w2[h][4]=c1.x; w2[h][5]=c1.y; w2[h][6]=c1.z; w2[h][7]=c1.w;
        }
    }

    const float* xin = input + (size_t)row0 * NF + f;

    // ---- rolled row loop with depth-2 register prefetch ----
    float x0 = xin[0];
    float x1 = xin[NF];

    #pragma unroll 2
    for (int r = 0; r < ROWS_PER_BLOCK; ++r) {
        const float x = x0;
        x0 = x1;
        const int rn = (r + 2 < ROWS_PER_BLOCK) ? (r + 2) : (ROWS_PER_BLOCK - 1);
        x1 = xin[(size_t)rn * NF];

        float h1[NH];
        #pragma unroll
        for (int h = 0; h < NH; ++h)
            h1[h] = fmaxf(fmaf(x, w1[h], bb1[h]), 0.0f);

        float acc[NH];
        #pragma unroll
        for (int k = 0; k < NH; ++k)       // fold init into h=0 FMA
            acc[k] = fmaf(h1[0], w2[0][k], bb2[k]);
        #pragma unroll
        for (int h = 1; h < NH; ++h) {
            #pragma unroll
            for (int k = 0; k < NH; ++k)
                acc[k] = fmaf(h1[h], w2[h][k], acc[k]);
        }

        float s = 0.0f;
        #pragma unroll
        for (int k = 0; k < NH; ++k)
            s = fmaf(fmaxf(acc[k], 0.0f), w3[k], s);

        sred[r][f] = s;
    }

    __syncthreads();

    // ---- store + reduce phase: wave w handles rows [8w, 8w+8) ----
    const int wave = threadIdx.x >> 6;
    const int lane = threadIdx.x & 63;
    #pragma unroll
    for (int rr = 0; rr < ROWS_PER_BLOCK / 4; ++rr) {
        const int r = wave * (ROWS_PER_BLOCK / 4) + rr;
        const float4 q = reinterpret_cast<const float4*>(&sred[r][0])[lane];
        reinterpret_cast<float4*>(out_w + (size_t)(row0 + r) * NF)[lane] = q;
        float v = q.x + q.y + q.z + q.w;
        #pragma unroll
        for (int off = 32; off > 0; off >>= 1)
            v += __shfl_xor(v, off, 64);
        if (lane == 0)
            out_sum[row0 + r] = v;
    }
}

extern "C" void kernel_launch(void* const* d_in, const int* in_sizes, int n_in,
                              void* d_out, int out_size, void* d_ws, size_t ws_size,
                              hipStream_t stream) {
    const float* input = (const float*)d_in[0];
    const float* W1    = (const float*)d_in[1];
    const float* b1    = (const float*)d_in[2];
    const float* W2    = (const float*)d_in[3];
    const float* b2    = (const float*)d_in[4];
    const float* W3    = (const float*)d_in[5];

    float* out = (float*)d_out;          // [B] sums, then [B,F] w
    float* out_sum = out;
    float* out_w   = out + NB;

    dim3 grid(NB / ROWS_PER_BLOCK);      // 1024 blocks
    dim3 block(NF);                      // 256 threads = 1 per feature

    // MEASUREMENT: launch twice (pure function, identical outputs).
    // dur_us = harness_overhead + 2*K isolates true kernel time K against the
    // ~70 us fixed poison/restore floor.
    NAM_49314814493074_kernel<<<grid, block, 0, stream>>>(
        input, W1, b1, W2, b2, W3, out_sum, out_w);
    NAM_49314814493074_kernel<<<grid, block, 0, stream>>>(
        input, W1, b1, W2, b2, W3, out_sum, out_w);
}

// Round 9
// 105.765 us; speedup vs baseline: 6.4717x; 6.4717x over previous
//
#include <hip/hip_runtime.h>

// Problem constants (match reference)
#define NB 32768   // batch rows
#define NF 256     // features
#define NH 8       // hidden dim
#define ROWS_PER_BLOCK 32
#define NPAIR (ROWS_PER_BLOCK / 2)   // 16 row-pairs

// One thread per feature; 96 MLP params scalar in registers (full unroll keeps
// them resident — round 8 proved rolled loops spill). KEY CHANGE vs round 7:
// compute TWO ROWS per step as packed f32x2 (v_pk_fma_f32 / v_pk_max_f32),
// halving dynamic instruction count and shrinking the unrolled body from
// ~28 KB (L1I thrash at ~30% issue) to ~13 KB. launch_bounds(256,2): VGPR cap
// 256 fits params + two 8-pair x chunks + f32x2 temps without spill.
// Results go to LDS only; one barrier; store+reduce phase emits coalesced
// dwordx4 out_w stores and per-row sum butterflies, fire-and-forget.

typedef float f32x2 __attribute__((ext_vector_type(2)));

static __device__ __forceinline__ f32x2 splat2(float v) {
    f32x2 r; r.x = v; r.y = v; return r;
}

__global__ __launch_bounds__(256, 2) void NAM_49314814493074_kernel(
    const float* __restrict__ input,   // [B, F]
    const float* __restrict__ W1,      // [F, 8]
    const float* __restrict__ b1,      // [F, 8]
    const float* __restrict__ W2,      // [F, 8, 8]
    const float* __restrict__ b2,      // [F, 8]
    const float* __restrict__ W3,      // [F, 8]
    float* __restrict__ out_sum,       // [B]
    float* __restrict__ out_w)         // [B, F]
{
    __shared__ float sred[ROWS_PER_BLOCK][NF];   // 32 KB

    const int f = threadIdx.x;                  // feature index 0..255
    const int row0 = blockIdx.x * ROWS_PER_BLOCK;

    // ---- params first: the only loads whose latency is ever exposed ----
    float w1[NH], bb1[NH], bb2[NH], w3[NH];
    float w2[NH][NH];
    {
        const float4* p1  = reinterpret_cast<const float4*>(W1 + (size_t)f * NH);
        const float4* pb1 = reinterpret_cast<const float4*>(b1 + (size_t)f * NH);
        const float4* pb2 = reinterpret_cast<const float4*>(b2 + (size_t)f * NH);
        const float4* p3  = reinterpret_cast<const float4*>(W3 + (size_t)f * NH);
        float4 a, b;
        a = p1[0]; b = p1[1];
        w1[0]=a.x; w1[1]=a.y; w1[2]=a.z; w1[3]=a.w; w1[4]=b.x; w1[5]=b.y; w1[6]=b.z; w1[7]=b.w;
        a = pb1[0]; b = pb1[1];
        bb1[0]=a.x; bb1[1]=a.y; bb1[2]=a.z; bb1[3]=a.w; bb1[4]=b.x; bb1[5]=b.y; bb1[6]=b.z; bb1[7]=b.w;
        a = pb2[0]; b = pb2[1];
        bb2[0]=a.x; bb2[1]=a.y; bb2[2]=a.z; bb2[3]=a.w; bb2[4]=b.x; bb2[5]=b.y; bb2[6]=b.z; bb2[7]=b.w;
        a = p3[0]; b = p3[1];
        w3[0]=a.x; w3[1]=a.y; w3[2]=a.z; w3[3]=a.w; w3[4]=b.x; w3[5]=b.y; w3[6]=b.z; w3[7]=b.w;

        const float4* p2 = reinterpret_cast<const float4*>(W2 + (size_t)f * NH * NH);
        #pragma unroll
        for (int h = 0; h < NH; ++h) {
            float4 c0 = p2[h * 2 + 0];
            float4 c1 = p2[h * 2 + 1];
            w2[h][0]=c0.x; w2[h][1]=c0.y; w2[h][2]=c0.z; w2[h][3]=c0.w;
            w2[h][4]=c1.x; w2[h][5]=c1.y; w2[h][6]=c1.z; w2[h][7]=c1.w;
        }
    }

    const float* xin = input + (size_t)row0 * NF + f;

    // ---- prefetch x in two chunks of 8 pairs (16 rows each) ----
    f32x2 xA[NPAIR / 2], xB[NPAIR / 2];
    #pragma unroll
    for (int p = 0; p < NPAIR / 2; ++p) {
        xA[p].x = xin[(size_t)(2 * p) * NF];
        xA[p].y = xin[(size_t)(2 * p + 1) * NF];
    }
    #pragma unroll
    for (int p = 0; p < NPAIR / 2; ++p) {
        xB[p].x = xin[(size_t)(16 + 2 * p) * NF];
        xB[p].y = xin[(size_t)(16 + 2 * p + 1) * NF];
    }

    const f32x2 zero2 = splat2(0.0f);

    // per-pair MLP: ~96 packed VALU ops for TWO rows; results to LDS only.
    auto computePairs = [&](f32x2 (&xb)[NPAIR / 2], int pair0) {
        #pragma unroll
        for (int p = 0; p < NPAIR / 2; ++p) {
            const f32x2 x = xb[p];

            f32x2 h1[NH];
            #pragma unroll
            for (int h = 0; h < NH; ++h)
                h1[h] = __builtin_elementwise_max(
                    __builtin_elementwise_fma(x, splat2(w1[h]), splat2(bb1[h])), zero2);

            f32x2 acc[NH];
            #pragma unroll
            for (int k = 0; k < NH; ++k)   // fold init into h=0 FMA
                acc[k] = __builtin_elementwise_fma(h1[0], splat2(w2[0][k]), splat2(bb2[k]));
            #pragma unroll
            for (int h = 1; h < NH; ++h) {
                #pragma unroll
                for (int k = 0; k < NH; ++k)
                    acc[k] = __builtin_elementwise_fma(h1[h], splat2(w2[h][k]), acc[k]);
            }

            f32x2 s = zero2;
            #pragma unroll
            for (int k = 0; k < NH; ++k)
                s = __builtin_elementwise_fma(
                    __builtin_elementwise_max(acc[k], zero2), splat2(w3[k]), s);

            const int r = (pair0 + p) * 2;
            sred[r][f]     = s.x;
            sred[r + 1][f] = s.y;
        }
    };

    computePairs(xA, 0);
    computePairs(xB, NPAIR / 2);

    __syncthreads();

    // ---- store + reduce phase: wave w handles rows [8w, 8w+8) ----
    const int wave = threadIdx.x >> 6;
    const int lane = threadIdx.x & 63;
    #pragma unroll
    for (int rr = 0; rr < ROWS_PER_BLOCK / 4; ++rr) {
        const int r = wave * (ROWS_PER_BLOCK / 4) + rr;
        const float4 q = reinterpret_cast<const float4*>(&sred[r][0])[lane];
        reinterpret_cast<float4*>(out_w + (size_t)(row0 + r) * NF)[lane] = q;
        float v = q.x + q.y + q.z + q.w;
        #pragma unroll
        for (int off = 32; off > 0; off >>= 1)
            v += __shfl_xor(v, off, 64);
        if (lane == 0)
            out_sum[row0 + r] = v;
    }
}

extern "C" void kernel_launch(void* const* d_in, const int* in_sizes, int n_in,
                              void* d_out, int out_size, void* d_ws, size_t ws_size,
                              hipStream_t stream) {
    const float* input = (const float*)d_in[0];
    const float* W1    = (const float*)d_in[1];
    const float* b1    = (const float*)d_in[2];
    const float* W2    = (const float*)d_in[3];
    const float* b2    = (const float*)d_in[4];
    const float* W3    = (const float*)d_in[5];

    float* out = (float*)d_out;          // [B] sums, then [B,F] w
    float* out_sum = out;
    float* out_w   = out + NB;

    dim3 grid(NB / ROWS_PER_BLOCK);      // 1024 blocks
    dim3 block(NF);                      // 256 threads = 1 per feature
    NAM_49314814493074_kernel<<<grid, block, 0, stream>>>(
        input, W1, b1, W2, b2, W3, out_sum, out_w);
}